// Round 4
// baseline (169.613 us; speedup 1.0000x reference)
//
#include <hip/hip_runtime.h>
#include <hip/hip_fp16.h>
#include <math.h>

// Problem constants
#define BB 4
#define HH 48
#define WW 48
#define DD 64
#define CC 2116          // 46*46 true column count (softmax stats)
#define HWp (HH*WW)      // 2304
#define PW 50            // zero-padded field width
#define PP (PW*PW)       // 2500 padded pixels

// slot space: j padded per-row 46->48 -> K width 2208 (dummies are zero)
#define SLOTW 48
#define NSLOT 2208
#define NGRP 276         // 2208/8 groups of 8 slots
#define KSPLIT0 1120     // 35*32; split1 = [1120,2208) = 34 iters
#define QW 2304          // F row width (v-domain = 48*48)
#define QROWS 2500       // F rows (u-domain = 50*50)

typedef __attribute__((ext_vector_type(8))) short short8;
typedef __attribute__((ext_vector_type(8))) _Float16 half8;
typedef __attribute__((ext_vector_type(4))) float float4v;

// ---------- workspace layout (byte offsets, all 16B-aligned) ----------
#define OFFB_GPAD  ((size_t)0)            // bf16 [B][2500][64]     1,280,000 B
#define OFFB_BGPAD ((size_t)1280000)      // bf16 [B][2500][64]     1,280,000 B
#define OFFB_E     ((size_t)2560000)      // f32  [B][2304]            36,864 B
#define OFFB_K1D   ((size_t)2596864)      // f32  [B][2208]            35,328 B
#define OFFB_BGT3  ((size_t)2632192)      // fp16 [B][192][2208]    3,391,488 B
#define OFFB_F     ((size_t)6023680)      // fp16 F [B][2500][2304] 46,080,000 B
#define OFFB_CA    ((size_t)52103680)     // fp16 CA [B][2304][2208] 40,697,856 B
#define OFFB_CAY   ((size_t)92801536)     // fp16 CAy [B][2304][2208] 40,697,856 B
#define OFFB_ACLP  ((size_t)133499392)    // f32  [2][B*2304][192]  14,155,776 B
// total 147,655,168 B (ws allocation is 256 MiB)

// ---------- helpers ----------
__device__ __forceinline__ ushort f2bf(float x) {
    unsigned u = __float_as_uint(x);
    return (ushort)((u + 0x7FFFu + ((u >> 16) & 1u)) >> 16);
}

__device__ __forceinline__ float waveReduceSum(float x) {
#pragma unroll
    for (int o = 32; o > 0; o >>= 1) x += __shfl_down(x, o, 64);
    return x;
}

__device__ __forceinline__ __half2 u2h2(uint u) {
    union { uint u; __half2 h; } c; c.u = u; return c.h;
}

// packed f32x2 -> bf16x2 (RNE), one instruction
__device__ __forceinline__ uint cvtpk_bf16(float lo, float hi) {
    uint r;
    asm("v_cvt_pk_bf16_f32 %0, %1, %2" : "=v"(r) : "v"(lo), "v"(hi));
    return r;
}

// exp(-50*tanh(z)) with tanh folded: = exp(-50 + 100/(e^{2z}+1))
__device__ __forceinline__ float softexp(float d, float mu, float isd) {
    float z = (d - mu) * isd;
    float E2 = __expf(z + z);
    float r = __builtin_amdgcn_rcpf(E2 + 1.f);
    return __expf(fmaf(100.f, r, -50.f));
}

// async 16B global->LDS (wave-uniform LDS base + lane*16)
typedef __attribute__((address_space(3))) void lds_void_t;
typedef __attribute__((address_space(1))) void gmem_void_t;
__device__ __forceinline__ void gld16(const ushort* g, ushort* lds) {
    __builtin_amdgcn_global_load_lds((gmem_void_t*)g, (lds_void_t*)lds, 16, 0, 0);
}

// ---------- build padded fields: gpad = bf16(g), bgpad = bf16(g*mask), e = sum_c bg^2 ----------
__global__ __launch_bounds__(256) void build_pads(const float* __restrict__ g,
                                                  const float* __restrict__ mask,
                                                  ushort* __restrict__ gpad,
                                                  ushort* __restrict__ bgpad,
                                                  float* __restrict__ e) {
    int w = threadIdx.x >> 6, c = threadIdx.x & 63;
    int q4 = blockIdx.x * 4 + w;         // [0, B*2500)
    int b = q4 / PP, q = q4 % PP;
    int yp = q / PW, xp = q % PW;
    size_t o = (size_t)q4 * DD + c;
    if (yp >= 1 && yp <= HH && xp >= 1 && xp <= WW) {
        int pix = (yp - 1) * WW + (xp - 1);
        float gv = g[((size_t)b * HWp + pix) * DD + c];
        float m  = mask[(size_t)b * HWp + pix];
        float bgv = gv * m;
        gpad[o]  = f2bf(gv);
        bgpad[o] = f2bf(bgv);
        float ss = waveReduceSum(bgv * bgv);
        if (c == 0) e[b * HWp + pix] = ss;
    } else {
        gpad[o] = 0;
        bgpad[o] = 0;
    }
}

// ---------- bgT3: fp16 [B][192][2208], row (dx*64+d)[v'] = bgI[v'+dx, d]; + k1d ----------
__global__ __launch_bounds__(256) void build_bgt3_k1d(const ushort* __restrict__ bgpad,
                                                      const float* __restrict__ e,
                                                      ushort* __restrict__ bgT3,
                                                      float* __restrict__ k1d) {
    int b = blockIdx.y;
    int t = threadIdx.x;
    if (blockIdx.x == 35) {
        // k1d[b][st]: 3x3 window sum of e at slot st=(jy,jx); zero for pad jx
#pragma unroll 1
        for (int st = t; st < NSLOT; st += 256) {
            int jy = st / SLOTW, jx = st - jy * SLOTW;
            float s = 0.f;
            if (jx < 46) {
                const float* eb = e + (size_t)b * HWp + jy * WW + jx;
#pragma unroll
                for (int ddy = 0; ddy < 3; ddy++)
#pragma unroll
                    for (int ddx = 0; ddx < 3; ddx++) s += eb[ddy * WW + ddx];
            }
            k1d[(size_t)b * NSLOT + st] = s;
        }
        return;
    }
    __shared__ ushort T[66 * 65];
    int jt = blockIdx.x;                 // 0..34 (tiles of 64 v'; last partial)
    const ushort* src = bgpad + (size_t)b * PP * DD;
    int lr = t >> 3, c8 = (t & 7) * 8;
#pragma unroll
    for (int pass = 0; pass < 2; pass++) {
        int r = lr + pass * 32;          // 0..63
        int v = jt * 64 + r;             // <= 34*64+63 = 2239 < 2304
        int vy = v / 48, vx = v - vy * 48;
        uint4 d = *(const uint4*)(src + (size_t)((vy + 1) * PW + (vx + 1)) * DD + c8);
        ushort tmp[8];
        *(uint4*)tmp = d;
#pragma unroll
        for (int u = 0; u < 8; u++) {
            float f = __uint_as_float((uint)tmp[u] << 16);   // bf16 -> f32
            __half h = __float2half_rn(f);
            T[r * 65 + c8 + u] = *(ushort*)&h;
        }
    }
    if (t < 16) {                        // halo rows 64, 65
        int r = 64 + (t >> 3);
        int c8b = (t & 7) * 8;
        int v = jt * 64 + r;             // <= 2241 < 2304
        int vy = v / 48, vx = v - vy * 48;
        uint4 d = *(const uint4*)(src + (size_t)((vy + 1) * PW + (vx + 1)) * DD + c8b);
        ushort tmp[8];
        *(uint4*)tmp = d;
#pragma unroll
        for (int u = 0; u < 8; u++) {
            float f = __uint_as_float((uint)tmp[u] << 16);
            __half h = __float2half_rn(f);
            T[r * 65 + c8b + u] = *(ushort*)&h;
        }
    }
    __syncthreads();
#pragma unroll
    for (int pass = 0; pass < 2; pass++) {
        int c = lr + pass * 32;          // d index
        int j8 = (t & 7) * 8;
        int col0 = jt * 64 + j8;
        if (col0 < NSLOT) {
#pragma unroll
            for (int dx = 0; dx < 3; dx++) {
                ushort tmp[8];
#pragma unroll
                for (int u = 0; u < 8; u++) tmp[u] = T[(j8 + u + dx) * 65 + c];
                *(uint4*)(bgT3 + ((size_t)b * 192 + dx * 64 + c) * NSLOT + col0) =
                    *(const uint4*)tmp;
            }
        }
    }
}

// ---------- fgemm: F[u,v] = sum_dx Q[u+dx,v+dx] as a K=192 GEMM (contiguous k!) ----------
// A'row(u) = gpad + u*64 (192 halves); B'row(v) = bgpad + ((vy+1)*50+vx+1)*64 (192 halves).
// Columns vx in {46,47} produce garbage (wrap) but are never consumed (pad slots).
__global__ __launch_bounds__(256) void fgemm(const ushort* __restrict__ gpad,
                                             const ushort* __restrict__ bgpad,
                                             __half* __restrict__ Fout) {
    __shared__ ushort As[2 * 4096];
    __shared__ ushort Bs[2 * 4096];
    int i0 = blockIdx.x;
    int b = (i0 & 7) >> 1;                    // batch pinned to XCD pair
    int tile = ((i0 >> 3) << 1) | (i0 & 1);   // 0..359, bijective
    int ty = tile / 18, tx = tile - ty * 18;  // 20 m-tiles x 18 n-tiles
    int m0 = ty * 128, n0 = tx * 128;
    const ushort* Ag = gpad + (size_t)b * PP * DD;
    const ushort* Bg = bgpad + (size_t)b * PP * DD;

    int tid = threadIdx.x;
    int l = tid & 63, w = tid >> 6;
    int quad = l >> 4, l15 = l & 15;
    int sw8 = (l15 >> 1) & 3;
    int wm = (w >> 1) * 64, wn = (w & 1) * 64;
    int rowInC = l >> 2;
    int cSw = (l & 3) ^ ((l >> 3) & 3);

    int baseA[2], baseB[2];
#pragma unroll
    for (int i = 0; i < 2; i++) {
        int rg = w * 2 + i;
        int r = rg * 16 + rowInC;
        int u = m0 + r; if (u > QROWS - 1) u = QROWS - 1;  // clamp; store-guarded
        int n = n0 + r;                                     // < 2304 always
        int vy = n / 48, vx = n - vy * 48;
        baseA[i] = u * DD + cSw * 8;
        baseB[i] = ((vy + 1) * PW + (vx + 1)) * DD + cSw * 8;
    }

    float4v acc[4][4];
#pragma unroll
    for (int i = 0; i < 4; i++)
#pragma unroll
        for (int j = 0; j < 4; j++) acc[i][j] = (float4v){0.f, 0.f, 0.f, 0.f};

    // prologue: k0 = 0
#pragma unroll
    for (int i = 0; i < 2; i++) {
        int rg = w * 2 + i;
        gld16(Ag + baseA[i], As + rg * 512);
        gld16(Bg + baseB[i], Bs + rg * 512);
    }

    int buf = 0;
    for (int k0 = 0; k0 < 192; k0 += 32) {
        __syncthreads();
        int nb = buf ^ 1;
        if (k0 + 32 < 192) {
#pragma unroll
            for (int i = 0; i < 2; i++) {
                int rg = w * 2 + i;
                gld16(Ag + baseA[i] + (k0 + 32), As + nb * 4096 + rg * 512);
                gld16(Bg + baseB[i] + (k0 + 32), Bs + nb * 4096 + rg * 512);
            }
        }
        const ushort* Ax = As + buf * 4096;
        const ushort* Bx = Bs + buf * 4096;
        short8 af[4], bf[4];
#pragma unroll
        for (int i = 0; i < 4; i++)
            af[i] = *(const short8*)&Ax[(wm + i * 16 + l15) * 32 + ((quad ^ sw8)) * 8];
#pragma unroll
        for (int j = 0; j < 4; j++)
            bf[j] = *(const short8*)&Bx[(wn + j * 16 + l15) * 32 + ((quad ^ sw8)) * 8];
#pragma unroll
        for (int i = 0; i < 4; i++)
#pragma unroll
            for (int j = 0; j < 4; j++)
                acc[i][j] = __builtin_amdgcn_mfma_f32_16x16x32_bf16(af[i], bf[j], acc[i][j], 0, 0, 0);
        buf = nb;
    }

    __half* C = Fout + (size_t)b * QROWS * QW;
#pragma unroll
    for (int i = 0; i < 4; i++) {
#pragma unroll
        for (int j = 0; j < 4; j++) {
            int n = n0 + wn + j * 16 + l15;
#pragma unroll
            for (int r = 0; r < 4; r++) {
                int m = m0 + wm + i * 16 + quad * 4 + r;
                if (m < QROWS) C[(size_t)m * QW + n] = __float2half(acc[i][j][r]);
            }
        }
    }
}

// ---------- fused CS (3 aligned dy-loads of F) + standardize + -50*tanh + softmax -> fp16 CA ----------
// 4 x-consecutive pixels per block (2304 blocks); thread t owns slot-group t for all 4 px.
// CS[(y,x),slot] = sum_dy F[(y+dy)*50 + x, slot + 48*dy]  -- all loads aligned uint4.
__global__ __launch_bounds__(320) void qrowsoft4(const __half* __restrict__ F,
                                                 const float* __restrict__ k1d,
                                                 ushort* __restrict__ CA) {
    __shared__ float red[8][321];    // transpose-reduce scratch; col 320 = results
    int i0 = blockIdx.x;
    int b = (i0 & 7) >> 1;                       // batch pinned to XCD pair
    int sub = ((i0 >> 3) << 1) | (i0 & 1);       // 0..575
    int y = sub / 12, xt = sub - y * 12;
    int x0 = xt * 4;

    int t = threadIdx.x;
    bool act = (t < NGRP);
    int jy = t / 6, jxb = (t - jy * 6) * 8;
    int slot0 = jy * SLOTW + jxb;
    bool vc6 = act && (jxb == 40);               // group containing pad slots 46,47

    __half2 acc[4][4];
#pragma unroll
    for (int p = 0; p < 4; p++)
#pragma unroll
        for (int k = 0; k < 4; k++) acc[p][k] = u2h2(0u);

    float k1v[8] = {0.f, 0.f, 0.f, 0.f, 0.f, 0.f, 0.f, 0.f};

    if (act) {
        const float* k1 = k1d + (size_t)b * NSLOT + slot0;
        float4 ka = *(const float4*)k1;
        float4 kb = *(const float4*)(k1 + 4);
        k1v[0] = ka.x; k1v[1] = ka.y; k1v[2] = ka.z; k1v[3] = ka.w;
        k1v[4] = kb.x; k1v[5] = kb.y; k1v[6] = kb.z; k1v[7] = kb.w;

#pragma unroll
        for (int dy = 0; dy < 3; dy++) {
            const __half* R = F + ((size_t)b * QROWS + (size_t)(y + dy) * PW + x0) * QW
                            + slot0 + dy * 48;
#pragma unroll
            for (int p = 0; p < 4; p++) {
                uint4 v4 = *(const uint4*)(R + (size_t)p * QW);
                acc[p][0] = __hadd2(acc[p][0], u2h2(v4.x));
                acc[p][1] = __hadd2(acc[p][1], u2h2(v4.y));
                acc[p][2] = __hadd2(acc[p][2], u2h2(v4.z));
                acc[p][3] = __hadd2(acc[p][3], u2h2(v4.w));
            }
        }
    }

    // purge pad-slot garbage (slots 46,47 of each jy row)
    if (vc6) {
#pragma unroll
        for (int p = 0; p < 4; p++) acc[p][3] = u2h2(0u);
    }

    // ---- phase A: per-pixel sum & sumsq of ds = k1 - 2*cs ----
#pragma unroll
    for (int p = 0; p < 4; p++) {
        float s1p = 0.f, s2p = 0.f;
#pragma unroll
        for (int k = 0; k < 4; k++) {
            float2 f = __half22float2(acc[p][k]);
            float d0 = k1v[2*k]   - 2.f * f.x;
            float d1 = k1v[2*k+1] - 2.f * f.y;
            s1p += d0 + d1;
            s2p = fmaf(d0, d0, fmaf(d1, d1, s2p));
        }
        red[p][t] = s1p;
        red[4 + p][t] = s2p;
    }
    __syncthreads();
    if (t < 128) {
        int v = t >> 4, sb = t & 15;
        float s = 0.f;
#pragma unroll
        for (int k = 0; k < 20; k++) s += red[v][sb + 16 * k];
#pragma unroll
        for (int o = 8; o > 0; o >>= 1) s += __shfl_down(s, o, 16);
        if (sb == 0) red[v][320] = s;
    }
    __syncthreads();
    float mu[4], isd[4];
#pragma unroll
    for (int p = 0; p < 4; p++) {
        float m = red[p][320] * (1.f / (float)CC);
        float ex2 = red[4 + p][320] * (1.f / (float)CC);
        mu[p] = m;
        isd[p] = rsqrtf(ex2 - m * m);
    }

    // ---- exp pass: pack unnormalized exp as bf16 pairs, accumulate es ----
    uint eb[4][4];
#pragma unroll
    for (int p = 0; p < 4; p++) {
        float es = 0.f;
#pragma unroll
        for (int k = 0; k < 4; k++) {
            float2 f = __half22float2(acc[p][k]);
            float d0 = k1v[2*k]   - 2.f * f.x;
            float d1 = k1v[2*k+1] - 2.f * f.y;
            if (k == 3 && vc6) { d0 = 1e9f; d1 = 1e9f; }   // pad slots -> ~e^-50 -> fp16 0
            float e0 = softexp(d0, mu[p], isd[p]);
            float e1 = softexp(d1, mu[p], isd[p]);
            es += e0 + e1;
            eb[p][k] = cvtpk_bf16(e0, e1);
        }
        red[p][t] = act ? es : 0.f;
    }
    __syncthreads();
    if (t < 64) {
        int v = t >> 4, sb = t & 15;
        float s = 0.f;
#pragma unroll
        for (int k = 0; k < 20; k++) s += red[v][sb + 16 * k];
#pragma unroll
        for (int o = 8; o > 0; o >>= 1) s += __shfl_down(s, o, 16);
        if (sb == 0) red[v][320] = s;
    }
    __syncthreads();

    // ---- normalize and store fp16 CA ----
    if (act) {
#pragma unroll
        for (int p = 0; p < 4; p++) {
            float iz = __builtin_amdgcn_rcpf(red[p][320]);
            uint o[4];
#pragma unroll
            for (int k = 0; k < 4; k++) {
                uint wv = eb[p][k];
                float lo = __uint_as_float(wv << 16) * iz;
                float hi = __uint_as_float(wv & 0xffff0000u) * iz;
                __half2 hh = __halves2half2(__float2half_rn(lo), __float2half_rn(hi));
                o[k] = *(uint*)&hh;
            }
            int pix = y * WW + x0 + p;
            ushort* wp = CA + ((size_t)b * HWp + pix) * (size_t)NSLOT + slot0;
            *(uint4*)wp = *(const uint4*)o;
        }
    }
}

// ---------- CAy[(y,x),v] = sum_dy CA[(y+1-dy)*48 + x, v - 48*dy]  (aligned gather) ----------
__global__ __launch_bounds__(320) void cay_k(const ushort* __restrict__ CAu,
                                             ushort* __restrict__ CAy) {
    int i0 = blockIdx.x;
    int b = (i0 & 7) >> 1;
    int sub = ((i0 >> 3) << 1) | (i0 & 1);       // 0..575
    int y = sub / 12, xt = sub - y * 12;
    int x0 = xt * 4;

    int t = threadIdx.x;
    if (t >= NGRP) return;
    int jy = t / 6, jxb = (t - jy * 6) * 8;
    int slot0 = jy * SLOTW + jxb;

    __half2 acc[4][4];
#pragma unroll
    for (int p = 0; p < 4; p++)
#pragma unroll
        for (int k = 0; k < 4; k++) acc[p][k] = u2h2(0u);

#pragma unroll
    for (int dy = 0; dy < 3; dy++) {
        int yy = y + 1 - dy;
        if (yy < 0 || yy >= 48) continue;
        if (jy < dy) continue;                   // v-underflow (group-uniform)
        const ushort* rp = CAu + ((size_t)b * HWp + yy * 48 + x0) * (size_t)NSLOT
                         + slot0 - 48 * dy;
#pragma unroll
        for (int p = 0; p < 4; p++) {
            uint4 v4 = *(const uint4*)(rp + (size_t)p * NSLOT);
            acc[p][0] = __hadd2(acc[p][0], u2h2(v4.x));
            acc[p][1] = __hadd2(acc[p][1], u2h2(v4.y));
            acc[p][2] = __hadd2(acc[p][2], u2h2(v4.z));
            acc[p][3] = __hadd2(acc[p][3], u2h2(v4.w));
        }
    }

#pragma unroll
    for (int p = 0; p < 4; p++) {
        uint o[4];
#pragma unroll
        for (int k = 0; k < 4; k++) {
            __half2 h = acc[p][k];
            o[k] = *(uint*)&h;
        }
        *(uint4*)(CAy + ((size_t)b * HWp + y * 48 + x0 + p) * (size_t)NSLOT + slot0) =
            *(const uint4*)o;
    }
}

// ---------- gemm4: P = CAy * bgT3^T (M=2304/b, N=192, K=2208, split-K=2, f32 partials) ----------
__global__ __launch_bounds__(256) void gemm4(const ushort* __restrict__ Am,
                                             const ushort* __restrict__ Bm,
                                             float* __restrict__ aclp) {
    __shared__ ushort As[2 * 4096];
    __shared__ ushort Bs[2 * 2048];
    int i0 = blockIdx.x;                 // 432 = 18 mt x 3 nt x 2 s x 4 b
    int z = i0 & 7;
    int b = z >> 1, s = z & 1;
    int tile = i0 >> 3;                  // 0..53
    int ty = tile / 3, tx = tile - ty * 3;
    int m0 = ty * 128, n0 = tx * 64;
    int kb = s ? KSPLIT0 : 0;
    int ke = s ? NSLOT : KSPLIT0;
    const ushort* Ab = Am + ((size_t)b * HWp + m0) * (size_t)NSLOT;
    const ushort* Bb = Bm + ((size_t)b * 192 + n0) * (size_t)NSLOT;

    int tid = threadIdx.x;
    int l = tid & 63, w = tid >> 6;
    int quad = l >> 4, l15 = l & 15;
    int sw8 = (l15 >> 1) & 3;
    int wm = w * 32;
    int rowInC = l >> 2;
    int cSw = (l & 3) ^ ((l >> 3) & 3);

    float4v acc[2][4];
#pragma unroll
    for (int i = 0; i < 2; i++)
#pragma unroll
        for (int j = 0; j < 4; j++) acc[i][j] = (float4v){0.f, 0.f, 0.f, 0.f};

#pragma unroll
    for (int i = 0; i < 2; i++) {
        int rg = w * 2 + i;
        gld16(Ab + (size_t)(rg * 16 + rowInC) * NSLOT + kb + cSw * 8, As + rg * 512);
    }
    gld16(Bb + (size_t)(w * 16 + rowInC) * NSLOT + kb + cSw * 8, Bs + w * 512);

    int buf = 0;
    for (int k0 = kb; k0 < ke; k0 += 32) {
        __syncthreads();
        int nb = buf ^ 1;
        if (k0 + 32 < ke) {
#pragma unroll
            for (int i = 0; i < 2; i++) {
                int rg = w * 2 + i;
                gld16(Ab + (size_t)(rg * 16 + rowInC) * NSLOT + (k0 + 32) + cSw * 8,
                      As + nb * 4096 + rg * 512);
            }
            gld16(Bb + (size_t)(w * 16 + rowInC) * NSLOT + (k0 + 32) + cSw * 8,
                  Bs + nb * 2048 + w * 512);
        }
        const ushort* Ax = As + buf * 4096;
        const ushort* Bx = Bs + buf * 2048;
        half8 af[2], bf[4];
#pragma unroll
        for (int i = 0; i < 2; i++)
            af[i] = *(const half8*)&Ax[(wm + i * 16 + l15) * 32 + ((quad ^ sw8)) * 8];
#pragma unroll
        for (int j = 0; j < 4; j++)
            bf[j] = *(const half8*)&Bx[(j * 16 + l15) * 32 + ((quad ^ sw8)) * 8];
#pragma unroll
        for (int i = 0; i < 2; i++)
#pragma unroll
            for (int j = 0; j < 4; j++)
                acc[i][j] = __builtin_amdgcn_mfma_f32_16x16x32_f16(af[i], bf[j], acc[i][j], 0, 0, 0);
        buf = nb;
    }

    float* C = aclp + ((size_t)s * (BB * HWp) + (size_t)b * HWp) * 192;
#pragma unroll
    for (int i = 0; i < 2; i++)
#pragma unroll
        for (int j = 0; j < 4; j++)
#pragma unroll
            for (int r = 0; r < 4; r++) {
                int m = m0 + wm + i * 16 + quad * 4 + r;
                int n = n0 + j * 16 + l15;
                C[(size_t)m * 192 + n] = acc[i][j][r];
            }
}

// ---------- final: acl = sum_dx sum_s P[(y, x+1-dx), dx*64+d]; ACL; concat; W2; ELU ----------
__global__ __launch_bounds__(256) void final_k3(const float* __restrict__ g,
                                                const float* __restrict__ mask,
                                                const float* __restrict__ aclp,
                                                const float* __restrict__ W2,
                                                const float* __restrict__ b2,
                                                float* __restrict__ out) {
    int w = threadIdx.x >> 6, d = threadIdx.x & 63;
    int pix = blockIdx.x * 4 + w;
    int b = pix / HWp, yx = pix % HWp;
    int y = yx / WW, x = yx % WW;

    __shared__ float con1[4][128];
    float acl = 0.f;
#pragma unroll
    for (int dx = 0; dx < 3; dx++) {
        int xs = x + 1 - dx;
        if (xs >= 0 && xs < WW) {
            size_t off = ((size_t)b * HWp + y * WW + xs) * 192 + dx * 64 + d;
            acl += aclp[off] + aclp[off + (size_t)BB * HWp * 192];
        }
    }

    float m = mask[pix];
    float gv = g[(size_t)pix * DD + d];
    float bgv = gv * m;
    float ACL = bgv + (acl / 9.f) * (1.f - m);
    con1[w][d] = gv;
    con1[w][64 + d] = ACL;
    __syncthreads();
    float accv = b2[d];
#pragma unroll 8
    for (int k = 0; k < 128; k++) accv = fmaf(con1[w][k], W2[k * 64 + d], accv);
    out[(size_t)pix * DD + d] = accv > 0.f ? accv : expm1f(accv);
}

extern "C" void kernel_launch(void* const* d_in, const int* in_sizes, int n_in,
                              void* d_out, int out_size, void* d_ws, size_t ws_size,
                              hipStream_t stream) {
    const float* g    = (const float*)d_in[0];
    const float* mask = (const float*)d_in[1];
    const float* W2   = (const float*)d_in[2];
    const float* b2   = (const float*)d_in[3];
    float* out = (float*)d_out;
    char* ws = (char*)d_ws;

    ushort* gpad  = (ushort*)(ws + OFFB_GPAD);
    ushort* bgpad = (ushort*)(ws + OFFB_BGPAD);
    float*  e     = (float*) (ws + OFFB_E);
    float*  k1d   = (float*) (ws + OFFB_K1D);
    ushort* bgT3  = (ushort*)(ws + OFFB_BGT3);
    __half* Fbuf  = (__half*)(ws + OFFB_F);
    ushort* CA    = (ushort*)(ws + OFFB_CA);
    ushort* CAy   = (ushort*)(ws + OFFB_CAY);
    float*  aclp  = (float*) (ws + OFFB_ACLP);

    build_pads<<<BB * PP / 4, 256, 0, stream>>>(g, mask, gpad, bgpad, e);
    build_bgt3_k1d<<<dim3(36, BB), 256, 0, stream>>>(bgpad, e, bgT3, k1d);

    fgemm<<<1440, 256, 0, stream>>>(gpad, bgpad, Fbuf);
    qrowsoft4<<<BB * HWp / 4, 320, 0, stream>>>(Fbuf, k1d, CA);

    cay_k<<<BB * HWp / 4, 320, 0, stream>>>(CA, CAy);
    gemm4<<<432, 256, 0, stream>>>(CAy, bgT3, aclp);

    final_k3<<<BB * HWp / 4, 256, 0, stream>>>(g, mask, aclp, W2, b2, out);
}